// Round 12
// baseline (240.425 us; speedup 1.0000x reference)
//
#include <hip/hip_runtime.h>

typedef __attribute__((ext_vector_type(8))) short bf16x8;   // 8 bf16 (4 VGPRs)
typedef __attribute__((ext_vector_type(4))) float f32x4;

#define KSV 45   // visual split-K (bf16 path): 45 * 24 * 64 = 69120
#define ZV_FB 72 // fallback f32-direct visual split-K
#define ZA 2     // audio split-K: 2 * 10 * 64 = 1280

// pack two f32 -> one dword of 2 bf16 (RNE)
__device__ __forceinline__ unsigned int pk2(float a, float b) {
    unsigned int r;
    asm("v_cvt_pk_bf16_f32 %0, %1, %2" : "=v"(r) : "v"(a), "v"(b));
    return r;
}
// global -> LDS direct copy, 16B per lane
__device__ __forceinline__ void gll16(void* lds, const void* g) {
    __builtin_amdgcn_global_load_lds(
        (__attribute__((address_space(1))) void*)(uintptr_t)g,
        (__attribute__((address_space(3))) void*)(uint32_t)(uintptr_t)lds,
        16, 0, 0);
}

// ---------------------------------------------------------------------------
// crop_cvt: cropped visual f32 -> Av bf16 [512][69120]. Pure coalesced stream.
// block = (row r, chunk p); chunk = 4608 contiguous f32 at c*46080+t*9216+4608.
// ---------------------------------------------------------------------------
__global__ __launch_bounds__(384) void crop_cvt(
    const float* __restrict__ v_1, const float* __restrict__ v_2,
    unsigned short* __restrict__ Av)
{
    const int b = blockIdx.x, tid = threadIdx.x;
    const int r = b / 15, p = b - r * 15;
    const float* src = ((r < 256) ? v_1 + (size_t)r * 138240
                                  : v_2 + (size_t)(r - 256) * 138240)
                     + (p % 3) * 46080 + (p / 3) * 9216 + 4608;
    unsigned short* dst = Av + (size_t)r * 69120 + p * 4608;
    #pragma unroll
    for (int j = 0; j < 3; ++j) {
        const int idx = j * 384 + tid;          // float4 index < 1152
        const float4 f = *(const float4*)(src + idx * 4);
        uint2 o; o.x = pk2(f.x, f.y); o.y = pk2(f.z, f.w);
        *(uint2*)(dst + idx * 4) = o;
    }
}

// ---------------------------------------------------------------------------
// wtrans: W_v [69120][512] f32 -> Wt [512][69120] bf16.
// 128k x 64n tile via LDS f32 [128][68] (16B-aligned rows, pad kills conflicts)
// Reads: 64B segments; writes: 256B contiguous per output row.
// ---------------------------------------------------------------------------
__global__ __launch_bounds__(256) void wtrans(
    const float* __restrict__ W, unsigned short* __restrict__ Wt)
{
    __shared__ float T[128 * 68];
    const int b = blockIdx.x, tid = threadIdx.x;
    const int k0 = (b >> 3) * 128, n0 = (b & 7) * 64;

    const int kr_b = tid >> 2;            // 0..63
    const int c    = tid & 3;
    #pragma unroll
    for (int pass = 0; pass < 2; ++pass) {
        const int kr = pass * 64 + kr_b;
        #pragma unroll
        for (int q = 0; q < 4; ++q) {
            const int col = q * 16 + c * 4;
            const float4 f = *(const float4*)(W + (size_t)(k0 + kr) * 512 + n0 + col);
            *(float4*)&T[kr * 68 + col] = f;
        }
    }
    __syncthreads();

    const int n_l = tid >> 2, q = tid & 3;
    float v[32];
    #pragma unroll
    for (int j = 0; j < 32; ++j) v[j] = T[(q * 32 + j) * 68 + n_l];
    unsigned short* dp = Wt + (size_t)(n0 + n_l) * 69120 + k0 + q * 32;
    #pragma unroll
    for (int g = 0; g < 4; ++g) {
        uint4 o;
        o.x = pk2(v[8 * g + 0], v[8 * g + 1]); o.y = pk2(v[8 * g + 2], v[8 * g + 3]);
        o.z = pk2(v[8 * g + 4], v[8 * g + 5]); o.w = pk2(v[8 * g + 6], v[8 * g + 7]);
        *(uint4*)(dp + g * 8) = o;
    }
}

// ---------------------------------------------------------------------------
// gemm_bf16 (r6-verified): C = A[512,K] * Bt^T, A,Bt bf16 row-major-K.
// Tile 128x128, BK=64, 4 waves. Both operands via global_load_lds (16B/lane),
// pre-swizzled source addresses, [row][8 units]^XOR(row&7) LDS layout.
// ---------------------------------------------------------------------------
__global__ __launch_bounds__(256, 3) void gemm_bf16(
    const unsigned short* __restrict__ Abf,
    const unsigned short* __restrict__ Bt,
    float* __restrict__ part, int K, int ksteps)
{
    __shared__ uint4 As[1024];
    __shared__ uint4 Bs[1024];

    const int tid = threadIdx.x;
    const int blk = blockIdx.x;
    const int cpx = gridDim.x >> 3;
    const int lin = (blk & 7) * cpx + (blk >> 3);
    const int z  = lin >> 4;
    const int mn = lin & 15;
    const int m0 = (mn >> 2) * 128;
    const int n0 = (mn & 3) * 128;
    const int k0 = z * ksteps * 64;
    part += (size_t)z * 262144;

    const int wid = tid >> 6, lane = tid & 63;
    const int l15 = lane & 15, lk = lane >> 4;
    const int wm = (wid >> 1) * 64, wn = (wid & 1) * 64;

    int ua[2][4], ub[2][4];
    #pragma unroll
    for (int kh = 0; kh < 2; ++kh) {
        #pragma unroll
        for (int mi = 0; mi < 4; ++mi) {
            const int row = wm + mi * 16 + l15;
            ua[kh][mi] = row * 8 + ((kh * 4 + lk) ^ (row & 7));
        }
        #pragma unroll
        for (int ni = 0; ni < 4; ++ni) {
            const int nn = wn + ni * 16 + l15;
            ub[kh][ni] = nn * 8 + ((kh * 4 + lk) ^ (nn & 7));
        }
    }

    const unsigned short* bsrc[4];
    const unsigned short* asrc[4];
    #pragma unroll
    for (int i = 0; i < 4; ++i) {
        const int u = i * 256 + tid;
        const int rw = u >> 3, cc = u & 7;
        bsrc[i] = Bt  + (size_t)(n0 + rw) * K + k0 + ((cc ^ (rw & 7)) * 8);
        asrc[i] = Abf + (size_t)(m0 + rw) * K + k0 + ((cc ^ (rw & 7)) * 8);
    }

    f32x4 acc[4][4];
    #pragma unroll
    for (int mi = 0; mi < 4; ++mi)
        #pragma unroll
        for (int ni = 0; ni < 4; ++ni) acc[mi][ni] = f32x4{0.f, 0.f, 0.f, 0.f};

    for (int ks = 0; ks < ksteps; ++ks) {
        #pragma unroll
        for (int i = 0; i < 4; ++i)
            gll16(Bs + i * 256 + wid * 64, bsrc[i]);
        #pragma unroll
        for (int i = 0; i < 4; ++i)
            gll16(As + i * 256 + wid * 64, asrc[i]);
        __syncthreads();

        #pragma unroll
        for (int kh = 0; kh < 2; ++kh) {
            bf16x8 af[4], bfr[4];
            #pragma unroll
            for (int mi = 0; mi < 4; ++mi) af[mi] = __builtin_bit_cast(bf16x8, As[ua[kh][mi]]);
            #pragma unroll
            for (int ni = 0; ni < 4; ++ni) bfr[ni] = __builtin_bit_cast(bf16x8, Bs[ub[kh][ni]]);
            #pragma unroll
            for (int mi = 0; mi < 4; ++mi)
                #pragma unroll
                for (int ni = 0; ni < 4; ++ni)
                    acc[mi][ni] = __builtin_amdgcn_mfma_f32_16x16x32_bf16(af[mi], bfr[ni], acc[mi][ni], 0, 0, 0);
        }
        __syncthreads();

        #pragma unroll
        for (int i = 0; i < 4; ++i) { bsrc[i] += 64; asrc[i] += 64; }
    }

    #pragma unroll
    for (int mi = 0; mi < 4; ++mi)
        #pragma unroll
        for (int ni = 0; ni < 4; ++ni) {
            const int col = n0 + wn + ni * 16 + l15;
            #pragma unroll
            for (int r = 0; r < 4; ++r) {
                const int row = m0 + wm + mi * 16 + lk * 4 + r;
                part[(size_t)row * 512 + col] = acc[mi][ni][r];
            }
        }
}

// ---------------------------------------------------------------------------
// fgemm (r10-verified): f32-direct GEMM, 128x128, BK=64, synchronous staging.
// Used for audio (CROP=0) and as visual fallback (CROP=1) on small ws.
// ---------------------------------------------------------------------------
template<int CROP>
__global__ __launch_bounds__(256, 4) void fgemm(
    const float* __restrict__ s1, const float* __restrict__ s2,
    const float* __restrict__ W, float* __restrict__ part, int ksteps)
{
    __shared__ uint4 As[1024];
    __shared__ uint4 Bs[1024];

    const int tid = threadIdx.x;
    const int blk = blockIdx.x;
    const int cpx = gridDim.x >> 3;
    const int lin = (blk & 7) * cpx + (blk >> 3);
    const int z  = lin >> 4;
    const int m0 = ((lin >> 2) & 3) * 128;
    const int n0 = (lin & 3) * 128;
    const int k0 = z * ksteps * 64;
    part += (size_t)z * 262144;

    const int a_row  = tid >> 1;
    const int a_half = tid & 1;
    const int grow = m0 + a_row;
    const int ROWSTR = CROP ? 138240 : 1280;
    const float* abase = (grow < 256) ? s1 + (size_t)grow * ROWSTR
                                      : s2 + (size_t)(grow - 256) * ROWSTR;

    const int bcol  = 2 * (tid >> 2);
    const int b_oct = tid & 3;
    const float* bp = W + (size_t)(k0 + b_oct * 8) * 512 + n0 + bcol;

    const int wid = tid >> 6, lane = tid & 63;
    const int l15 = lane & 15, lk = lane >> 4;
    const int wm = (wid >> 1) * 64, wn = (wid & 1) * 64;

    int ua[2][4], ub[2][4];
    #pragma unroll
    for (int kh = 0; kh < 2; ++kh) {
        #pragma unroll
        for (int mi = 0; mi < 4; ++mi) {
            const int row = wm + mi * 16 + l15;
            ua[kh][mi] = row * 8 + ((kh * 4 + lk) ^ (row & 7));
        }
        #pragma unroll
        for (int ni = 0; ni < 4; ++ni) {
            const int nn = wn + ni * 16 + l15;
            ub[kh][ni] = nn * 8 + ((kh * 4 + lk) ^ (nn & 7));
        }
    }

    f32x4 acc[4][4];
    #pragma unroll
    for (int mi = 0; mi < 4; ++mi)
        #pragma unroll
        for (int ni = 0; ni < 4; ++ni) acc[mi][ni] = f32x4{0.f, 0.f, 0.f, 0.f};

    int kc = k0;
    for (int ks = 0; ks < ksteps; ++ks) {
        int aoffu;
        if (CROP) {
            const int p = kc / 4608;
            const int j = kc - p * 4608;
            const int c3 = p % 3, t9 = p / 3;
            aoffu = c3 * 46080 + t9 * 9216 + 4608 + j;
        } else {
            aoffu = kc;
        }
        #pragma unroll
        for (int ph = 0; ph < 2; ++ph) {
            {
                const float* ap = abase + aoffu + ph * 32 + a_half * 16;
                const float4 f0 = *(const float4*)ap;
                const float4 f1 = *(const float4*)(ap + 4);
                const float4 f2 = *(const float4*)(ap + 8);
                const float4 f3 = *(const float4*)(ap + 12);
                const int x0 = ph * 4 + a_half * 2;
                uint4 w0, w1;
                w0.x = pk2(f0.x, f0.y); w0.y = pk2(f0.z, f0.w);
                w0.z = pk2(f1.x, f1.y); w0.w = pk2(f1.z, f1.w);
                w1.x = pk2(f2.x, f2.y); w1.y = pk2(f2.z, f2.w);
                w1.z = pk2(f3.x, f3.y); w1.w = pk2(f3.z, f3.w);
                As[a_row * 8 + ( x0      ^ (a_row & 7))] = w0;
                As[a_row * 8 + ((x0 + 1) ^ (a_row & 7))] = w1;
            }
            {
                const float* bq = bp + (size_t)(kc - k0 + ph * 32) * 512;
                float2 bv[8];
                #pragma unroll
                for (int r = 0; r < 8; ++r)
                    bv[r] = *(const float2*)(bq + (size_t)r * 512);
                const int u = ph * 4 + b_oct;
                uint4 p0, p1;
                p0.x = pk2(bv[0].x, bv[1].x); p0.y = pk2(bv[2].x, bv[3].x);
                p0.z = pk2(bv[4].x, bv[5].x); p0.w = pk2(bv[6].x, bv[7].x);
                p1.x = pk2(bv[0].y, bv[1].y); p1.y = pk2(bv[2].y, bv[3].y);
                p1.z = pk2(bv[4].y, bv[5].y); p1.w = pk2(bv[6].y, bv[7].y);
                Bs[(bcol)     * 8 + (u ^ ( bcol      & 7))] = p0;
                Bs[(bcol + 1) * 8 + (u ^ ((bcol + 1) & 7))] = p1;
            }
        }
        __syncthreads();

        #pragma unroll
        for (int kh = 0; kh < 2; ++kh) {
            bf16x8 af[4], bfr[4];
            #pragma unroll
            for (int mi = 0; mi < 4; ++mi) af[mi] = __builtin_bit_cast(bf16x8, As[ua[kh][mi]]);
            #pragma unroll
            for (int ni = 0; ni < 4; ++ni) bfr[ni] = __builtin_bit_cast(bf16x8, Bs[ub[kh][ni]]);
            #pragma unroll
            for (int mi = 0; mi < 4; ++mi)
                #pragma unroll
                for (int ni = 0; ni < 4; ++ni)
                    acc[mi][ni] = __builtin_amdgcn_mfma_f32_16x16x32_bf16(af[mi], bfr[ni], acc[mi][ni], 0, 0, 0);
        }
        __syncthreads();
        kc += 64;
    }

    #pragma unroll
    for (int mi = 0; mi < 4; ++mi)
        #pragma unroll
        for (int ni = 0; ni < 4; ++ni) {
            const int col = n0 + wn + ni * 16 + l15;
            #pragma unroll
            for (int r = 0; r < 4; ++r) {
                const int row = m0 + wm + mi * 16 + lk * 4 + r;
                part[(size_t)row * 512 + col] = acc[mi][ni][r];
            }
        }
}

// ---------- reduce split-K partials + row L2 normalization ----------
__global__ __launch_bounds__(256) void norm_kernel(
    const float* __restrict__ partA, const float* __restrict__ partV,
    float* __restrict__ Aout, float* __restrict__ Vout, int nzV)
{
    const int row = blockIdx.x;
    const int tid = threadIdx.x;
    const bool isV = row >= 512;
    const int r = isV ? (row - 512) : row;
    const int c0 = tid, c1 = tid + 256;

    float v0 = 0.f, v1 = 0.f;
    if (isV) {
        for (int zz = 0; zz < nzV; ++zz) {
            const float* p = partV + (size_t)zz * 262144 + (size_t)r * 512;
            v0 += p[c0]; v1 += p[c1];
        }
    } else {
        #pragma unroll
        for (int zz = 0; zz < ZA; ++zz) {
            const float* p = partA + (size_t)zz * 262144 + (size_t)r * 512;
            v0 += p[c0]; v1 += p[c1];
        }
    }

    float ss = v0 * v0 + v1 * v1;
    #pragma unroll
    for (int off = 32; off > 0; off >>= 1) ss += __shfl_down(ss, off);
    __shared__ float sbuf[4];
    if ((tid & 63) == 0) sbuf[tid >> 6] = ss;
    __syncthreads();
    const float total = sbuf[0] + sbuf[1] + sbuf[2] + sbuf[3];
    const float inv = 1.f / fmaxf(sqrtf(total), 1e-12f);

    float* outp = (isV ? Vout : Aout) + (size_t)r * 512;
    outp[c0] = v0 * inv;
    outp[c1] = v1 * inv;
}

// ---------------------------------------------------------------------------
// similarity: S = Anorm . Vnorm^T; den[row&255] += sum exp; diag -> num
// ---------------------------------------------------------------------------
__global__ __launch_bounds__(256) void sim_kernel(
    const float* __restrict__ A, const float* __restrict__ V,
    float* __restrict__ den, float* __restrict__ num)
{
    __shared__ uint4 As[2][256];
    __shared__ uint4 Bs[2][256];

    const int tid = threadIdx.x;
    const int m0 = (blockIdx.x >> 3) * 64;
    const int n0 = (blockIdx.x & 7) * 64;
    const int nsteps = 16;

    const int a_row = tid >> 2, a_kb = tid & 3;
    const int b_col = tid & 63, b_kb = tid >> 6;
    const int a_u = (a_kb * 64 + a_row) ^ (a_kb << 1);
    const int b_u = (b_kb * 64 + b_col) ^ (b_kb << 1);

    const float* abase = A + (size_t)(m0 + a_row) * 512;
    const float* bptr  = V + (size_t)(n0 + b_col) * 512 + b_kb * 8;
    int aoff = a_kb * 8;

    const int lane = tid & 63, wid = tid >> 6;
    const int wrow = (wid >> 1) * 32, wcol = (wid & 1) * 32;
    const int l15 = lane & 15, lk = lane >> 4;

    int ra[2], rb[2];
    #pragma unroll
    for (int m = 0; m < 2; ++m) ra[m] = (lk * 64 + wrow + m * 16 + l15) ^ (lk << 1);
    #pragma unroll
    for (int n = 0; n < 2; ++n) rb[n] = (lk * 64 + wcol + n * 16 + l15) ^ (lk << 1);

    f32x4 acc[2][2];
    #pragma unroll
    for (int m = 0; m < 2; ++m)
        #pragma unroll
        for (int n = 0; n < 2; ++n) acc[m][n] = f32x4{0.f, 0.f, 0.f, 0.f};

    float4 A0 = *(const float4*)(abase + aoff);
    float4 A1 = *(const float4*)(abase + aoff + 4);
    float4 B0 = *(const float4*)bptr;
    float4 B1 = *(const float4*)(bptr + 4);

    for (int ks = 0; ks < nsteps; ++ks) {
        const int cur = ks & 1;
        const bool more = (ks + 1 < nsteps);
        float4 A0n, A1n, B0n, B1n;
        if (more) {
            aoff += 32; bptr += 32;
            A0n = *(const float4*)(abase + aoff);
            A1n = *(const float4*)(abase + aoff + 4);
            B0n = *(const float4*)bptr;
            B1n = *(const float4*)(bptr + 4);
        }
        uint4 pa;
        pa.x = pk2(A0.x, A0.y); pa.y = pk2(A0.z, A0.w);
        pa.z = pk2(A1.x, A1.y); pa.w = pk2(A1.z, A1.w);
        As[cur][a_u] = pa;
        uint4 pb;
        pb.x = pk2(B0.x, B0.y); pb.y = pk2(B0.z, B0.w);
        pb.z = pk2(B1.x, B1.y); pb.w = pk2(B1.z, B1.w);
        Bs[cur][b_u] = pb;
        __syncthreads();

        bf16x8 af[2], bfr[2];
        #pragma unroll
        for (int m = 0; m < 2; ++m) af[m] = __builtin_bit_cast(bf16x8, As[cur][ra[m]]);
        #pragma unroll
        for (int n = 0; n < 2; ++n) bfr[n] = __builtin_bit_cast(bf16x8, Bs[cur][rb[n]]);
        #pragma unroll
        for (int m = 0; m < 2; ++m)
            #pragma unroll
            for (int n = 0; n < 2; ++n)
                acc[m][n] = __builtin_amdgcn_mfma_f32_16x16x32_bf16(af[m], bfr[n], acc[m][n], 0, 0, 0);

        if (more) { A0 = A0n; A1 = A1n; B0 = B0n; B1 = B1n; }
    }

    #pragma unroll
    for (int m = 0; m < 2; ++m) {
        float rs[4] = {0.f, 0.f, 0.f, 0.f};
        #pragma unroll
        for (int n = 0; n < 2; ++n) {
            const int col = n0 + wcol + n * 16 + l15;
            #pragma unroll
            for (int r = 0; r < 4; ++r) {
                const int row = m0 + wrow + m * 16 + lk * 4 + r;
                const float e = __expf(acc[m][n][r]);
                rs[r] += e;
                if (((row - col) & 255) == 0) atomicAdd(num + (row & 255), e);
            }
        }
        #pragma unroll
        for (int r = 0; r < 4; ++r) {
            float v = rs[r];
            v += __shfl_xor(v, 1);
            v += __shfl_xor(v, 2);
            v += __shfl_xor(v, 4);
            v += __shfl_xor(v, 8);
            if (l15 == 0) {
                const int row = m0 + wrow + m * 16 + lk * 4 + r;
                atomicAdd(den + (row & 255), v);
            }
        }
    }
}

// ---------- zero den/num accumulators ----------
__global__ __launch_bounds__(512) void zero_kernel(float* __restrict__ p) {
    p[threadIdx.x] = 0.f;
}

// ---------- a1.a2 and v1.v2 dots -> num += exp(dot) ----------
__global__ __launch_bounds__(256) void dots_kernel(
    const float* __restrict__ A, const float* __restrict__ V,
    float* __restrict__ num)
{
    const int b = blockIdx.x;
    const int i = b & 255;
    const float* X = (b < 256) ? A : V;
    const float* x = X + (size_t)i * 512;
    const float* y = X + (size_t)(i + 256) * 512;
    const int tid = threadIdx.x;
    float d = x[tid] * y[tid] + x[tid + 256] * y[tid + 256];
    #pragma unroll
    for (int off = 32; off > 0; off >>= 1) d += __shfl_down(d, off);
    __shared__ float sbuf[4];
    if ((tid & 63) == 0) sbuf[tid >> 6] = d;
    __syncthreads();
    if (tid == 0) atomicAdd(num + i, __expf(sbuf[0] + sbuf[1] + sbuf[2] + sbuf[3]));
}

// ---------- final: loss = mean(log den - log num) ----------
__global__ __launch_bounds__(256) void final_kernel(
    const float* __restrict__ den, const float* __restrict__ num,
    float* __restrict__ out)
{
    const int tid = threadIdx.x;
    float v = logf(den[tid]) - logf(num[tid]);
    #pragma unroll
    for (int off = 32; off > 0; off >>= 1) v += __shfl_down(v, off);
    __shared__ float sbuf[4];
    if ((tid & 63) == 0) sbuf[tid >> 6] = v;
    __syncthreads();
    if (tid == 0) out[0] = (sbuf[0] + sbuf[1] + sbuf[2] + sbuf[3]) * (1.f / 256.f);
}

// ---------- launch ----------
extern "C" void kernel_launch(void* const* d_in, const int* in_sizes, int n_in,
                              void* d_out, int out_size, void* d_ws, size_t ws_size,
                              hipStream_t stream)
{
    (void)in_sizes; (void)n_in; (void)out_size;
    const float* a_1 = (const float*)d_in[0];
    const float* v_1 = (const float*)d_in[1];
    const float* a_2 = (const float*)d_in[2];
    const float* v_2 = (const float*)d_in[3];
    const float* W_a = (const float*)d_in[4];
    const float* W_v = (const float*)d_in[5];
    float* out = (float*)d_out;

    // bf16 tier needs: den/num + norms + partA(2) + partV(45) + Av + Wt
    const size_t need_bf16 = 4ull * (512 + 262144ull * (2 + 2 + KSV))
                           + 2ull * 2ull * 35389440ull;      // ~193 MB
    const bool BF = ws_size >= need_bf16;
    const int nzV = BF ? KSV : ZV_FB;

    float* cur   = (float*)d_ws;
    float* den   = cur; cur += 256;
    float* num   = cur; cur += 256;
    float* Anorm = cur; cur += 262144;
    float* Vnorm = cur; cur += 262144;
    float* partA = cur; cur += (size_t)ZA * 262144;
    float* partV = cur; cur += (size_t)nzV * 262144;
    unsigned short* Av = (unsigned short*)cur;
    unsigned short* Wt = Av + 35389440ull;

    zero_kernel<<<1, 512, 0, stream>>>(den);   // zeros den[256]+num[256]

    if (BF) {
        crop_cvt<<<7680, 384, 0, stream>>>(v_1, v_2, Av);
        wtrans<<<4320, 256, 0, stream>>>(W_v, Wt);
        gemm_bf16<<<16 * KSV, 256, 0, stream>>>(Av, Wt, partV, 69120, 24);
    } else {
        fgemm<1><<<16 * ZV_FB, 256, 0, stream>>>(v_1, v_2, W_v, partV, 12);
    }
    fgemm<0><<<16 * ZA, 256, 0, stream>>>(a_1, a_2, W_a, partA, 10);

    norm_kernel<<<1024, 256, 0, stream>>>(partA, partV, Anorm, Vnorm, nzV);
    sim_kernel<<<64, 256, 0, stream>>>(Anorm, Vnorm, den, num);
    dots_kernel<<<512, 256, 0, stream>>>(Anorm, Vnorm, num);
    final_kernel<<<1, 256, 0, stream>>>(den, num, out);
}